// Round 6
// baseline (712.881 us; speedup 1.0000x reference)
//
#include <hip/hip_runtime.h>
#include <hip/hip_bf16.h>

typedef unsigned short ushort_t;
typedef __attribute__((ext_vector_type(8))) short bf16x8;
typedef __attribute__((ext_vector_type(4))) float f32x4;

__device__ __forceinline__ float bf2f(ushort_t u) {
    union { unsigned int i; float f; } v; v.i = ((unsigned int)u) << 16; return v.f;
}
__device__ __forceinline__ ushort_t f2bf(float f) {
    unsigned int u = __float_as_uint(f);
    unsigned int r = u + 0x7FFFu + ((u >> 16) & 1u);
    return (ushort_t)(r >> 16);
}
__device__ __forceinline__ float ldf(const void* p, size_t i, int isf) {
    return isf ? ((const float*)p)[i] : bf2f(((const ushort_t*)p)[i]);
}

// ---------------- dtype probe ----------------
__global__ void probe_dtype_k(const void* __restrict__ x, int* __restrict__ flag) {
    int t = threadIdx.x;
    const float* xf = (const float*)x;
    int bad = 0;
    for (int i = t; i < 2048; i += 256) {
        unsigned int u = __float_as_uint(xf[i]);
        unsigned int e = (u >> 23) & 0xFFu;
        if (e >= 0xC0u) bad = 1;
    }
    __shared__ int s_bad;
    if (t == 0) s_bad = 0;
    __syncthreads();
    if (bad) atomicOr(&s_bad, 1);
    __syncthreads();
    if (t == 0) flag[0] = s_bad ? 0 : 1;  // 1 = fp32 inputs
}

// ---------------- CSR build ----------------
__global__ void count_dst_k(const int* __restrict__ ei, int* __restrict__ cnt, int E) {
    int e = blockIdx.x * 256 + threadIdx.x;
    if (e < E) atomicAdd(&cnt[ei[E + e]], 1);
}

__global__ __launch_bounds__(256) void scan1_k(const int* __restrict__ cntA, const int* __restrict__ cntB,
                                               int* __restrict__ offA, int* __restrict__ offB,
                                               int* __restrict__ sums, int n, int nChunks) {
    int set = blockIdx.y;
    const int* cnt = set ? cntB : cntA;
    int* off = set ? offB : offA;
    __shared__ int s[256];
    int t = threadIdx.x;
    int idx = blockIdx.x * 1024 + t * 4;
    int v[4];
#pragma unroll
    for (int i = 0; i < 4; ++i) v[i] = (idx + i < n) ? cnt[idx + i] : 0;
    int tsum = v[0] + v[1] + v[2] + v[3];
    s[t] = tsum;
    __syncthreads();
    for (int d = 1; d < 256; d <<= 1) {
        int x = (t >= d) ? s[t - d] : 0;
        __syncthreads();
        s[t] += x;
        __syncthreads();
    }
    int run = s[t] - tsum;
    if (t == 255) sums[set * nChunks + blockIdx.x] = s[255];
#pragma unroll
    for (int i = 0; i < 4; ++i) { if (idx + i < n) off[idx + i] = run; run += v[i]; }
}

__global__ __launch_bounds__(256) void scan2_k(int* __restrict__ sums, int nChunks) {
    __shared__ int s[256];
    int t = threadIdx.x;
    for (int set = 0; set < 2; ++set) {
        int v = (t < nChunks) ? sums[set * nChunks + t] : 0;
        s[t] = v;
        __syncthreads();
        for (int d = 1; d < 256; d <<= 1) {
            int x = (t >= d) ? s[t - d] : 0;
            __syncthreads();
            s[t] += x;
            __syncthreads();
        }
        if (t < nChunks) sums[set * nChunks + t] = s[t] - v;  // exclusive
        __syncthreads();
    }
}

__global__ __launch_bounds__(256) void scan3_k(int* __restrict__ offA, int* __restrict__ offB,
                                               const int* __restrict__ sums, int n, int nChunks, int E) {
    int set = blockIdx.y;
    int* off = set ? offB : offA;
    int base = sums[set * nChunks + blockIdx.x];
    int idx = blockIdx.x * 1024 + threadIdx.x * 4;
#pragma unroll
    for (int i = 0; i < 4; ++i) { if (idx + i < n) off[idx + i] += base; }
    if (blockIdx.x == 0 && threadIdx.x == 0) off[n] = E;
}

// packed CSR entry: .x = src node, .y = weight bits
__global__ void fill_csr_k(const int* __restrict__ ei, const void* __restrict__ ew,
                           const int* __restrict__ off, int* __restrict__ cur,
                           uint2* __restrict__ pairs, int E,
                           const int* __restrict__ flagp) {
    int isf = *flagp;
    int e = blockIdx.x * 256 + threadIdx.x;
    if (e >= E) return;
    int d = ei[E + e];
    int p = off[d] + atomicAdd(&cur[d], 1);
    pairs[p] = make_uint2((unsigned)ei[e], __float_as_uint(ldf(ew, e, isf)));
}

// ---------------- weight prep: transposed bf16 [DOUT][K], skip folded in ----------------
__global__ void prep_bandT_k(ushort_t* __restrict__ Wt, int K, int colOff,
                             const void* __restrict__ A, const void* __restrict__ B, int n,
                             const int* __restrict__ flagp) {
    int isf = *flagp;
    int i = blockIdx.x * 256 + threadIdx.x;
    if (i >= n) return;  // n = 128*K
    int k = i >> 7, c = i & 127;
    float v = ldf(A, (size_t)k * 128 + c, isf);
    if (B) v += ldf(B, (size_t)k * 128 + c, isf);
    Wt[(size_t)(colOff + c) * K + k] = f2bf(v);
}

__global__ void prep_decT_k(ushort_t* __restrict__ Wdt, const void* __restrict__ W,
                            const int* __restrict__ flagp) {
    int isf = *flagp;
    int i = blockIdx.x * 256 + threadIdx.x;  // 32768
    int k = i >> 8, c = i & 255;
    Wdt[(size_t)c * 128 + k] = f2bf(ldf(W, (size_t)k * 256 + c, isf));
}

struct BiasJob { const void* a; const void* b; float* dst; int n; };
struct BiasJobs { BiasJob j[8]; };
__global__ void prep_bias_k(BiasJobs jobs, const int* __restrict__ flagp) {
    int isf = *flagp;
    BiasJob jb = jobs.j[blockIdx.x];
    int t = threadIdx.x;
    if (t < jb.n) {
        float v = ldf(jb.a, t, isf);
        if (jb.b) v += ldf(jb.b, t, isf);
        jb.dst[t] = v;
    }
}

// ---------------- MFMA GEMM (internal bf16 A): Y = A[M x K] @ Wt[DOUT x K] ----------------
template<int K, int DOUT>
__global__ __launch_bounds__(256) void gemm_mfma_k(
    const ushort_t* __restrict__ A, const ushort_t* __restrict__ Wt,
    ushort_t* __restrict__ Y, int M) {
    constexpr int NT = DOUT / 16;
    int tid = threadIdx.x;
    int wave = tid >> 6, lane = tid & 63;
    int q = lane >> 4, l15 = lane & 15;
    int arow = blockIdx.x * 64 + wave * 16 + l15;
    int rowc = arow < M ? arow : M - 1;
    f32x4 acc[NT];
#pragma unroll
    for (int t = 0; t < NT; ++t) acc[t] = (f32x4){0.f, 0.f, 0.f, 0.f};
#pragma unroll
    for (int kc = 0; kc < K; kc += 32) {
        bf16x8 a = *(const bf16x8*)(A + (size_t)rowc * K + kc + q * 8);
#pragma unroll
        for (int t = 0; t < NT; ++t) {
            bf16x8 b = *(const bf16x8*)(Wt + (size_t)(t * 16 + l15) * K + kc + q * 8);
            acc[t] = __builtin_amdgcn_mfma_f32_16x16x32_bf16(a, b, acc[t], 0, 0, 0);
        }
    }
    int outRowBase = blockIdx.x * 64 + wave * 16 + q * 4;
#pragma unroll
    for (int t = 0; t < NT; ++t) {
        int col = t * 16 + l15;
#pragma unroll
        for (int i = 0; i < 4; ++i) {
            int r = outRowBase + i;
            if (r < M) Y[(size_t)r * DOUT + col] = f2bf(acc[t][i]);
        }
    }
}

// ---------------- layer-1 MFMA GEMM reading raw x (dtype per flag) with PE fused ----------------
__global__ __launch_bounds__(256) void gemm_mfma_x_k(
    const void* __restrict__ X, const ushort_t* __restrict__ Wt,
    ushort_t* __restrict__ Y, int M, const void* __restrict__ pe,
    const int* __restrict__ flagp) {
    constexpr int K = 96, DOUT = 384, NT = DOUT / 16;
    __shared__ float pes[96];
    int isf = *flagp;
    int tid = threadIdx.x;
    if (tid < 96) pes[tid] = ldf(pe, tid, isf);
    __syncthreads();
    int wave = tid >> 6, lane = tid & 63;
    int q = lane >> 4, l15 = lane & 15;
    int arow = blockIdx.x * 64 + wave * 16 + l15;
    int rowc = arow < M ? arow : M - 1;
    f32x4 acc[NT];
#pragma unroll
    for (int t = 0; t < NT; ++t) acc[t] = (f32x4){0.f, 0.f, 0.f, 0.f};
#pragma unroll
    for (int kc = 0; kc < K; kc += 32) {
        float va[8];
        size_t base = (size_t)rowc * K + kc + q * 8;
        if (isf) {
            float4 u0 = *(const float4*)((const float*)X + base);
            float4 u1 = *(const float4*)((const float*)X + base + 4);
            va[0] = u0.x; va[1] = u0.y; va[2] = u0.z; va[3] = u0.w;
            va[4] = u1.x; va[5] = u1.y; va[6] = u1.z; va[7] = u1.w;
        } else {
            const ushort_t* xp = (const ushort_t*)X + base;
#pragma unroll
            for (int i = 0; i < 8; ++i) va[i] = bf2f(xp[i]);
        }
        bf16x8 a;
        short* ap = (short*)&a;
#pragma unroll
        for (int i = 0; i < 8; ++i) ap[i] = (short)f2bf(va[i] + pes[kc + q * 8 + i]);
#pragma unroll
        for (int t = 0; t < NT; ++t) {
            bf16x8 b = *(const bf16x8*)(Wt + (size_t)(t * 16 + l15) * K + kc + q * 8);
            acc[t] = __builtin_amdgcn_mfma_f32_16x16x32_bf16(a, b, acc[t], 0, 0, 0);
        }
    }
    int outRowBase = blockIdx.x * 64 + wave * 16 + q * 4;
#pragma unroll
    for (int t = 0; t < NT; ++t) {
        int col = t * 16 + l15;
#pragma unroll
        for (int i = 0; i < 4; ++i) {
            int r = outRowBase + i;
            if (r < M) Y[(size_t)r * DOUT + col] = f2bf(acc[t][i]);
        }
    }
}

// ---------------- fused prop(in)+prop(out)+combine, x8-unrolled gather for MLP ----------------
__device__ __forceinline__ void gather8(
    const uint2* __restrict__ pairs, const ushort_t* __restrict__ base, int ldY,
    int eBeg, int eEnd, float& out0, float& out1) {
    float f0[8] = {0.f, 0.f, 0.f, 0.f, 0.f, 0.f, 0.f, 0.f};
    float f1[8] = {0.f, 0.f, 0.f, 0.f, 0.f, 0.f, 0.f, 0.f};
    int e = eBeg;
    for (; e + 8 <= eEnd; e += 8) {
        uint2 p[8];
#pragma unroll
        for (int u = 0; u < 8; ++u) p[u] = pairs[e + u];
        unsigned v[8];
#pragma unroll
        for (int u = 0; u < 8; ++u) v[u] = *(const unsigned*)(base + (size_t)p[u].x * ldY);
#pragma unroll
        for (int u = 0; u < 8; ++u) {
            float w = __uint_as_float(p[u].y);
            f0[u] += w * bf2f((ushort_t)(v[u] & 0xffffu));
            f1[u] += w * bf2f((ushort_t)(v[u] >> 16));
        }
    }
    if (e + 4 <= eEnd) {
        uint2 p[4];
#pragma unroll
        for (int u = 0; u < 4; ++u) p[u] = pairs[e + u];
        unsigned v[4];
#pragma unroll
        for (int u = 0; u < 4; ++u) v[u] = *(const unsigned*)(base + (size_t)p[u].x * ldY);
#pragma unroll
        for (int u = 0; u < 4; ++u) {
            float w = __uint_as_float(p[u].y);
            f0[u] += w * bf2f((ushort_t)(v[u] & 0xffffu));
            f1[u] += w * bf2f((ushort_t)(v[u] >> 16));
        }
        e += 4;
    }
    for (; e < eEnd; ++e) {
        uint2 p = pairs[e];
        unsigned v = *(const unsigned*)(base + (size_t)p.x * ldY);
        float w = __uint_as_float(p.y);
        f0[0] += w * bf2f((ushort_t)(v & 0xffffu));
        f1[0] += w * bf2f((ushort_t)(v >> 16));
    }
    out0 = ((f0[0] + f0[1]) + (f0[2] + f0[3])) + ((f0[4] + f0[5]) + (f0[6] + f0[7]));
    out1 = ((f1[0] + f1[1]) + (f1[2] + f1[3])) + ((f1[4] + f1[5]) + (f1[6] + f1[7]));
}

__global__ __launch_bounds__(256) void prop_combine_k(
    const ushort_t* __restrict__ Y, int ldY,
    const int* __restrict__ offI, const uint2* __restrict__ prI,
    const int* __restrict__ offO, const uint2* __restrict__ prO,
    const void* __restrict__ Cin, const void* __restrict__ Cout,
    const float* __restrict__ bin, const float* __restrict__ bout,
    const ushort_t* __restrict__ res, int ldR, int colR, const float* __restrict__ res_b,
    ushort_t* __restrict__ H, int M, int relu, const int* __restrict__ flagp) {
    int isf = *flagp;
    int node = blockIdx.x * 4 + (threadIdx.x >> 6);
    int lane = threadIdx.x & 63;
    if (node >= M) return;
    float i0, i1, o0, o1;
    gather8(prI, Y + lane * 2,       ldY, offI[node], offI[node + 1], i0, i1);
    gather8(prO, Y + 128 + lane * 2, ldY, offO[node], offO[node + 1], o0, o1);
    int j = lane * 2;
    float ci = ldf(Cin, node, isf), co = ldf(Cout, node, isf);
    float r0 = bf2f(res[(size_t)node * ldR + colR + j]);
    float r1 = bf2f(res[(size_t)node * ldR + colR + j + 1]);
    float v0 = ci * (i0 + bin[j])     + co * (o0 + bout[j])     + r0;
    float v1 = ci * (i1 + bin[j + 1]) + co * (o1 + bout[j + 1]) + r1;
    if (res_b) { v0 += res_b[j]; v1 += res_b[j + 1]; }
    if (relu) { v0 = fmaxf(v0, 0.f); v1 = fmaxf(v1, 0.f); }
    *(unsigned*)(H + (size_t)node * 128 + j) =
        ((unsigned)f2bf(v1) << 16) | (unsigned)f2bf(v0);
}

// ---------------- decoder: normalize + MFMA logits (classes=rows) + coalesced writes ----------------
__global__ __launch_bounds__(256) void decoder_mfma_k(
    const ushort_t* __restrict__ h3, const ushort_t* __restrict__ Wdt,  // [256][128] bf16
    const float* __restrict__ biasDec, void* __restrict__ d_out, int M,
    const int* __restrict__ flagp) {
    __shared__ ushort_t embLds[64 * 136];
    __shared__ float sb[256];
    int isf = *flagp;
    int tid = threadIdx.x;
    sb[tid] = biasDec[tid];
    int rowBase = blockIdx.x * 64;
    // phase A: normalize 64 rows into embLds (bf16). No global writes here.
    {
        int r = tid >> 2;
        int c0 = (tid & 3) * 32;
        int grow = rowBase + r;
        uint4 u[4] = {};
        if (grow < M) {
            const uint4* p = (const uint4*)(h3 + (size_t)grow * 128 + c0);
            u[0] = p[0]; u[1] = p[1]; u[2] = p[2]; u[3] = p[3];
        }
        float v[32];
#pragma unroll
        for (int b = 0; b < 4; ++b) {
            unsigned w[4] = {u[b].x, u[b].y, u[b].z, u[b].w};
#pragma unroll
            for (int i = 0; i < 4; ++i) {
                v[b * 8 + 2 * i]     = bf2f((ushort_t)(w[i] & 0xffffu));
                v[b * 8 + 2 * i + 1] = bf2f((ushort_t)(w[i] >> 16));
            }
        }
        float ss = 0.f;
#pragma unroll
        for (int i = 0; i < 32; ++i) ss += v[i] * v[i];
        ss += __shfl_xor(ss, 1, 64);
        ss += __shfl_xor(ss, 2, 64);
        float inv = 1.0f / fmaxf(sqrtf(ss), 1e-12f);
#pragma unroll
        for (int i = 0; i < 32; ++i) v[i] *= inv;
        unsigned* lp = (unsigned*)&embLds[r * 136 + c0];
#pragma unroll
        for (int i = 0; i < 16; ++i)
            lp[i] = ((unsigned)f2bf(v[2 * i + 1]) << 16) | (unsigned)f2bf(v[2 * i]);
    }
    __syncthreads();
    // phase A2: fully-coalesced emb write from embLds
    {
        int rowsHere = M - rowBase; if (rowsHere > 64) rowsHere = 64;
        int total = rowsHere * 128;
        if (isf) {
            float* dst = (float*)d_out + (size_t)M * 256 + (size_t)rowBase * 128;
            for (int idx = tid * 4; idx < total; idx += 1024) {
                int r = idx >> 7, c = idx & 127;
                const ushort_t* sp = &embLds[r * 136 + c];
                float4 o = make_float4(bf2f(sp[0]), bf2f(sp[1]), bf2f(sp[2]), bf2f(sp[3]));
                *(float4*)(dst + idx) = o;
            }
        } else {
            ushort_t* dst = (ushort_t*)d_out + (size_t)M * 256 + (size_t)rowBase * 128;
            for (int idx = tid * 4; idx < total; idx += 1024) {
                int r = idx >> 7, c = idx & 127;
                uint2 o = *(const uint2*)&embLds[r * 136 + c];  // 8B-aligned: 136*2=272=8*34
                *(uint2*)(dst + idx) = o;
            }
        }
    }
    // phase B: logits via MFMA, operands swapped: rows=classes, cols=nodes
    int wave = tid >> 6, lane = tid & 63, q = lane >> 4, l15 = lane & 15;
    f32x4 acc[16];
#pragma unroll
    for (int t = 0; t < 16; ++t) acc[t] = (f32x4){0.f, 0.f, 0.f, 0.f};
    int ldsRow = wave * 16 + l15;  // node index within block
#pragma unroll
    for (int kc = 0; kc < 128; kc += 32) {
        bf16x8 a = *(const bf16x8*)(&embLds[ldsRow * 136 + kc + q * 8]);
#pragma unroll
        for (int t = 0; t < 16; ++t) {
            bf16x8 b = *(const bf16x8*)(Wdt + (size_t)(t * 16 + l15) * 128 + kc + q * 8);
            // SWAPPED: W as A-operand (rows=classes), emb as B-operand (cols=nodes)
            acc[t] = __builtin_amdgcn_mfma_f32_16x16x32_bf16(b, a, acc[t], 0, 0, 0);
        }
    }
    // lane (q,l15): node = rowBase + wave*16 + l15; classes = t*16 + q*4 + i
    int node = rowBase + wave * 16 + l15;
#pragma unroll
    for (int t = 0; t < 16; ++t) {
#pragma unroll
        for (int i = 0; i < 4; ++i) acc[t][i] += sb[t * 16 + q * 4 + i];
    }
    float mx = acc[0][0];
#pragma unroll
    for (int t = 0; t < 16; ++t) {
#pragma unroll
        for (int i = 0; i < 4; ++i) mx = fmaxf(mx, acc[t][i]);
    }
    mx = fmaxf(mx, __shfl_xor(mx, 16, 64));
    mx = fmaxf(mx, __shfl_xor(mx, 32, 64));
    float sm = 0.f;
#pragma unroll
    for (int t = 0; t < 16; ++t) {
#pragma unroll
        for (int i = 0; i < 4; ++i) sm += __expf(acc[t][i] - mx);
    }
    sm += __shfl_xor(sm, 16, 64);
    sm += __shfl_xor(sm, 32, 64);
    float offv = mx + __logf(sm);
    if (node < M) {
        if (isf) {
            float* op = (float*)d_out + (size_t)node * 256 + q * 4;
#pragma unroll
            for (int t = 0; t < 16; ++t) {
                float4 o = make_float4(acc[t][0] - offv, acc[t][1] - offv,
                                       acc[t][2] - offv, acc[t][3] - offv);
                *(float4*)(op + t * 16) = o;
            }
        } else {
            ushort_t* op = (ushort_t*)d_out + (size_t)node * 256 + q * 4;
#pragma unroll
            for (int t = 0; t < 16; ++t) {
                unsigned lo = ((unsigned)f2bf(acc[t][1] - offv) << 16) | (unsigned)f2bf(acc[t][0] - offv);
                unsigned hi = ((unsigned)f2bf(acc[t][3] - offv) << 16) | (unsigned)f2bf(acc[t][2] - offv);
                *(uint2*)(op + t * 16) = make_uint2(lo, hi);
            }
        }
    }
}

extern "C" void kernel_launch(void* const* d_in, const int* in_sizes, int n_in,
                              void* d_out, int out_size, void* d_ws, size_t ws_size,
                              hipStream_t stream) {
    const int N = in_sizes[0] / 96;
    const int E = in_sizes[2];

    const void* x      = d_in[0];
    const int*  ei_in  = (const int*)d_in[1];
    const void* ew_in  = d_in[2];
    const int*  ei_out = (const int*)d_in[3];
    const void* ew_out = d_in[4];
    const void* pe     = d_in[5];

    const void *W_mi[3], *W_mo[3], *W_sk[3], *b_mi[3], *b_mo[3], *b_si[3], *b_so[3], *C_i[3], *C_o[3];
    for (int l = 0; l < 3; ++l) {
        int base = 6 + l * 9;
        W_mi[l] = d_in[base + 0];
        W_mo[l] = d_in[base + 1];
        W_sk[l] = d_in[base + 2];
        b_mi[l] = d_in[base + 3];
        b_mo[l] = d_in[base + 4];
        b_si[l] = d_in[base + 5];
        b_so[l] = d_in[base + 6];
        C_i[l]  = d_in[base + 7];
        C_o[l]  = d_in[base + 8];
    }
    const void* res1_W = d_in[33];
    const void* res1_b = d_in[34];
    const void* dec_W  = d_in[35];
    const void* dec_b  = d_in[36];

    // ---- workspace (~80 MB) ----
    char* ws = (char*)d_ws;
    size_t off = 0;
    auto alloc = [&](size_t bytes) -> void* {
        void* p = ws + off;
        off = (off + bytes + 255) & ~(size_t)255;
        return p;
    };
    const int nChunks = (N + 1023) / 1024;
    int*   flag    = (int*)alloc(4);
    int*   off_in  = (int*)alloc((size_t)(N + 1) * 4);
    int*   cnt_in  = (int*)alloc((size_t)2 * N * 4);
    int*   cur_in  = cnt_in + N;
    uint2* pr_in   = (uint2*)alloc((size_t)E * 8);
    int*   off_out = (int*)alloc((size_t)(N + 1) * 4);
    int*   cnt_out = (int*)alloc((size_t)2 * N * 4);
    int*   cur_out = cnt_out + N;
    uint2* pr_out  = (uint2*)alloc((size_t)E * 8);
    int*   sums    = (int*)alloc((size_t)2 * nChunks * 4);
    ushort_t* Wt1  = (ushort_t*)alloc((size_t)384 * 96 * 2);
    ushort_t* Wt2  = (ushort_t*)alloc((size_t)256 * 128 * 2);
    ushort_t* Wt3  = (ushort_t*)alloc((size_t)256 * 128 * 2);
    ushort_t* Wdt  = (ushort_t*)alloc((size_t)256 * 128 * 2);
    float* biasBlk = (float*)alloc((size_t)1152 * 4);
    float* bin1 = biasBlk, *bout1 = biasBlk + 128, *bin2 = biasBlk + 256, *bout2 = biasBlk + 384;
    float* bin3 = biasBlk + 512, *bout3 = biasBlk + 640, *res1b = biasBlk + 768, *decb = biasBlk + 896;
    ushort_t* Yb  = (ushort_t*)alloc((size_t)N * 384 * 2);
    ushort_t* H1  = (ushort_t*)alloc((size_t)N * 128 * 2);
    ushort_t* H2  = (ushort_t*)alloc((size_t)N * 128 * 2);
    ushort_t* H3  = H1;  // H1 dead once layer-2 combine produced H2

    // ---- dtype probe ----
    probe_dtype_k<<<1, 256, 0, stream>>>(x, flag);

    // ---- CSR build ----
    hipMemsetAsync(cnt_in, 0, (size_t)2 * N * 4, stream);
    hipMemsetAsync(cnt_out, 0, (size_t)2 * N * 4, stream);
    int egrid = (E + 255) / 256;
    count_dst_k<<<egrid, 256, 0, stream>>>(ei_in, cnt_in, E);
    count_dst_k<<<egrid, 256, 0, stream>>>(ei_out, cnt_out, E);
    {
        dim3 g(nChunks, 2);
        scan1_k<<<g, 256, 0, stream>>>(cnt_in, cnt_out, off_in, off_out, sums, N, nChunks);
        scan2_k<<<1, 256, 0, stream>>>(sums, nChunks);
        scan3_k<<<g, 256, 0, stream>>>(off_in, off_out, sums, N, nChunks, E);
    }
    fill_csr_k<<<egrid, 256, 0, stream>>>(ei_in, ew_in, off_in, cur_in, pr_in, E, flag);
    fill_csr_k<<<egrid, 256, 0, stream>>>(ei_out, ew_out, off_out, cur_out, pr_out, E, flag);

    // ---- weight prep (transposed bf16; skip folded into main) ----
    prep_bandT_k<<<48, 256, 0, stream>>>(Wt1, 96, 0,   W_mi[0], W_sk[0], 128 * 96, flag);
    prep_bandT_k<<<48, 256, 0, stream>>>(Wt1, 96, 128, W_mo[0], W_sk[0], 128 * 96, flag);
    prep_bandT_k<<<48, 256, 0, stream>>>(Wt1, 96, 256, res1_W, (const void*)nullptr, 128 * 96, flag);
    prep_bandT_k<<<64, 256, 0, stream>>>(Wt2, 128, 0,   W_mi[1], W_sk[1], 128 * 128, flag);
    prep_bandT_k<<<64, 256, 0, stream>>>(Wt2, 128, 128, W_mo[1], W_sk[1], 128 * 128, flag);
    prep_bandT_k<<<64, 256, 0, stream>>>(Wt3, 128, 0,   W_mi[2], W_sk[2], 128 * 128, flag);
    prep_bandT_k<<<64, 256, 0, stream>>>(Wt3, 128, 128, W_mo[2], W_sk[2], 128 * 128, flag);
    prep_decT_k<<<128, 256, 0, stream>>>(Wdt, dec_W, flag);
    {
        BiasJobs jb;
        jb.j[0] = {b_mi[0], b_si[0], bin1, 128};
        jb.j[1] = {b_mo[0], b_so[0], bout1, 128};
        jb.j[2] = {b_mi[1], b_si[1], bin2, 128};
        jb.j[3] = {b_mo[1], b_so[1], bout2, 128};
        jb.j[4] = {b_mi[2], b_si[2], bin3, 128};
        jb.j[5] = {b_mo[2], b_so[2], bout3, 128};
        jb.j[6] = {res1_b, nullptr, res1b, 128};
        jb.j[7] = {dec_b, nullptr, decb, 256};
        prep_bias_k<<<8, 256, 0, stream>>>(jb, flag);
    }

    int gBlocks = (N + 63) / 64;
    int pgrid = (N + 3) / 4;

    // ---- layer 1: fused x+PE 96x384 GEMM (main_in | main_out | res) ----
    gemm_mfma_x_k<<<gBlocks, 256, 0, stream>>>(x, Wt1, Yb, N, pe, flag);
    prop_combine_k<<<pgrid, 256, 0, stream>>>(Yb, 384,
        off_in, pr_in, off_out, pr_out,
        C_i[0], C_o[0], bin1, bout1, Yb, 384, 256, res1b, H1, N, 1, flag);
    // ---- layer 2 ----
    gemm_mfma_k<128, 256><<<gBlocks, 256, 0, stream>>>(H1, Wt2, Yb, N);
    prop_combine_k<<<pgrid, 256, 0, stream>>>(Yb, 256,
        off_in, pr_in, off_out, pr_out,
        C_i[1], C_o[1], bin2, bout2, H1, 128, 0, (const float*)nullptr, H2, N, 1, flag);
    // ---- layer 3 ----
    gemm_mfma_k<128, 256><<<gBlocks, 256, 0, stream>>>(H2, Wt3, Yb, N);
    prop_combine_k<<<pgrid, 256, 0, stream>>>(Yb, 256,
        off_in, pr_in, off_out, pr_out,
        C_i[2], C_o[2], bin3, bout3, H2, 128, 0, (const float*)nullptr, H3, N, 0, flag);
    // ---- decoder ----
    decoder_mfma_k<<<gBlocks, 256, 0, stream>>>(H3, Wdt, decb, d_out, N, flag);
}

// Round 7
// 674.300 us; speedup vs baseline: 1.0572x; 1.0572x over previous
//
#include <hip/hip_runtime.h>
#include <hip/hip_bf16.h>

typedef unsigned short ushort_t;
typedef __attribute__((ext_vector_type(8))) short bf16x8;
typedef __attribute__((ext_vector_type(4))) float f32x4;

__device__ __forceinline__ float bf2f(ushort_t u) {
    union { unsigned int i; float f; } v; v.i = ((unsigned int)u) << 16; return v.f;
}
__device__ __forceinline__ ushort_t f2bf(float f) {
    unsigned int u = __float_as_uint(f);
    unsigned int r = u + 0x7FFFu + ((u >> 16) & 1u);
    return (ushort_t)(r >> 16);
}
__device__ __forceinline__ float ldf(const void* p, size_t i, int isf) {
    return isf ? ((const float*)p)[i] : bf2f(((const ushort_t*)p)[i]);
}

// ---------------- dtype probe ----------------
__global__ void probe_dtype_k(const void* __restrict__ x, int* __restrict__ flag) {
    int t = threadIdx.x;
    const float* xf = (const float*)x;
    int bad = 0;
    for (int i = t; i < 2048; i += 256) {
        unsigned int u = __float_as_uint(xf[i]);
        unsigned int e = (u >> 23) & 0xFFu;
        if (e >= 0xC0u) bad = 1;
    }
    __shared__ int s_bad;
    if (t == 0) s_bad = 0;
    __syncthreads();
    if (bad) atomicOr(&s_bad, 1);
    __syncthreads();
    if (t == 0) flag[0] = s_bad ? 0 : 1;  // 1 = fp32 inputs
}

// ---------------- CSR build (both edge sets via blockIdx.y) ----------------
__global__ void count_dst_k(const int* __restrict__ eiA, const int* __restrict__ eiB,
                            int* __restrict__ cntA, int* __restrict__ cntB, int E) {
    const int* ei = blockIdx.y ? eiB : eiA;
    int* cnt = blockIdx.y ? cntB : cntA;
    int e = blockIdx.x * 256 + threadIdx.x;
    if (e < E) atomicAdd(&cnt[ei[E + e]], 1);
}

__global__ __launch_bounds__(256) void scan1_k(const int* __restrict__ cntA, const int* __restrict__ cntB,
                                               int* __restrict__ offA, int* __restrict__ offB,
                                               int* __restrict__ sums, int n, int nChunks) {
    int set = blockIdx.y;
    const int* cnt = set ? cntB : cntA;
    int* off = set ? offB : offA;
    __shared__ int s[256];
    int t = threadIdx.x;
    int idx = blockIdx.x * 1024 + t * 4;
    int v[4];
#pragma unroll
    for (int i = 0; i < 4; ++i) v[i] = (idx + i < n) ? cnt[idx + i] : 0;
    int tsum = v[0] + v[1] + v[2] + v[3];
    s[t] = tsum;
    __syncthreads();
    for (int d = 1; d < 256; d <<= 1) {
        int x = (t >= d) ? s[t - d] : 0;
        __syncthreads();
        s[t] += x;
        __syncthreads();
    }
    int run = s[t] - tsum;
    if (t == 255) sums[set * nChunks + blockIdx.x] = s[255];
#pragma unroll
    for (int i = 0; i < 4; ++i) { if (idx + i < n) off[idx + i] = run; run += v[i]; }
}

__global__ __launch_bounds__(256) void scan2_k(int* __restrict__ sums, int nChunks) {
    __shared__ int s[256];
    int t = threadIdx.x;
    for (int set = 0; set < 2; ++set) {
        int v = (t < nChunks) ? sums[set * nChunks + t] : 0;
        s[t] = v;
        __syncthreads();
        for (int d = 1; d < 256; d <<= 1) {
            int x = (t >= d) ? s[t - d] : 0;
            __syncthreads();
            s[t] += x;
            __syncthreads();
        }
        if (t < nChunks) sums[set * nChunks + t] = s[t] - v;  // exclusive
        __syncthreads();
    }
}

__global__ __launch_bounds__(256) void scan3_k(int* __restrict__ offA, int* __restrict__ offB,
                                               const int* __restrict__ sums, int n, int nChunks, int E) {
    int set = blockIdx.y;
    int* off = set ? offB : offA;
    int base = sums[set * nChunks + blockIdx.x];
    int idx = blockIdx.x * 1024 + threadIdx.x * 4;
#pragma unroll
    for (int i = 0; i < 4; ++i) { if (idx + i < n) off[idx + i] += base; }
    if (blockIdx.x == 0 && threadIdx.x == 0) off[n] = E;
}

// packed CSR entry: .x = src node, .y = weight bits; both sets via blockIdx.y
__global__ void fill_csr_k(const int* __restrict__ eiA, const void* __restrict__ ewA,
                           const int* __restrict__ eiB, const void* __restrict__ ewB,
                           const int* __restrict__ offA, const int* __restrict__ offB,
                           int* __restrict__ curA, int* __restrict__ curB,
                           uint2* __restrict__ prA, uint2* __restrict__ prB,
                           int E, const int* __restrict__ flagp) {
    int isf = *flagp;
    const int* ei = blockIdx.y ? eiB : eiA;
    const void* ew = blockIdx.y ? ewB : ewA;
    const int* off = blockIdx.y ? offB : offA;
    int* cur = blockIdx.y ? curB : curA;
    uint2* pairs = blockIdx.y ? prB : prA;
    int e = blockIdx.x * 256 + threadIdx.x;
    if (e >= E) return;
    int d = ei[E + e];
    int p = off[d] + atomicAdd(&cur[d], 1);
    pairs[p] = make_uint2((unsigned)ei[e], __float_as_uint(ldf(ew, e, isf)));
}

// ---------------- fused weight prep: 7 band-transpose jobs + decoder transpose ----------------
struct PrepJob { const void* A; const void* B; ushort_t* dst; int K; int colOff; int n; int blkStart; int type; };
struct PrepJobs { PrepJob j[8]; };
__global__ void prep_all_k(PrepJobs jobs, const int* __restrict__ flagp) {
    int isf = *flagp;
    int bx = blockIdx.x;
    int ji = 0;
#pragma unroll
    for (int u = 0; u < 8; ++u) {
        if (bx >= jobs.j[u].blkStart) ji = u;
    }
    PrepJob jb = jobs.j[ji];
    int i = (bx - jb.blkStart) * 256 + threadIdx.x;
    if (i >= jb.n) return;
    if (jb.type == 0) {  // bandT: src [k][128] -> dst [(colOff+c)*K + k]
        int k = i >> 7, c = i & 127;
        float v = ldf(jb.A, i, isf);
        if (jb.B) v += ldf(jb.B, i, isf);
        jb.dst[(size_t)(jb.colOff + c) * jb.K + k] = f2bf(v);
    } else {             // decT: src [k][256] -> dst [c*128 + k]
        int k = i >> 8, c = i & 255;
        jb.dst[(size_t)c * 128 + k] = f2bf(ldf(jb.A, i, isf));
    }
}

struct BiasJob { const void* a; const void* b; float* dst; int n; };
struct BiasJobs { BiasJob j[8]; };
__global__ void prep_bias_k(BiasJobs jobs, const int* __restrict__ flagp) {
    int isf = *flagp;
    BiasJob jb = jobs.j[blockIdx.x];
    int t = threadIdx.x;
    if (t < jb.n) {
        float v = ldf(jb.a, t, isf);
        if (jb.b) v += ldf(jb.b, t, isf);
        jb.dst[t] = v;
    }
}

// ---------------- MFMA GEMM (internal bf16 A): Y = A[M x K] @ Wt[DOUT x K] ----------------
// LDS-staged epilogue: coalesced uint4 global stores.
template<int K, int DOUT>
__global__ __launch_bounds__(256) void gemm_mfma_k(
    const ushort_t* __restrict__ A, const ushort_t* __restrict__ Wt,
    ushort_t* __restrict__ Y, int M) {
    constexpr int NT = DOUT / 16;
    constexpr int LDW = DOUT + 8;
    __shared__ __align__(16) ushort_t Ylds[64 * LDW];
    int tid = threadIdx.x;
    int wave = tid >> 6, lane = tid & 63;
    int q = lane >> 4, l15 = lane & 15;
    int arow = blockIdx.x * 64 + wave * 16 + l15;
    int rowc = arow < M ? arow : M - 1;
    f32x4 acc[NT];
#pragma unroll
    for (int t = 0; t < NT; ++t) acc[t] = (f32x4){0.f, 0.f, 0.f, 0.f};
#pragma unroll
    for (int kc = 0; kc < K; kc += 32) {
        bf16x8 a = *(const bf16x8*)(A + (size_t)rowc * K + kc + q * 8);
#pragma unroll
        for (int t = 0; t < NT; ++t) {
            bf16x8 b = *(const bf16x8*)(Wt + (size_t)(t * 16 + l15) * K + kc + q * 8);
            acc[t] = __builtin_amdgcn_mfma_f32_16x16x32_bf16(a, b, acc[t], 0, 0, 0);
        }
    }
    int ldsRowBase = wave * 16 + q * 4;
#pragma unroll
    for (int t = 0; t < NT; ++t) {
        int col = t * 16 + l15;
#pragma unroll
        for (int i = 0; i < 4; ++i) Ylds[(ldsRowBase + i) * LDW + col] = f2bf(acc[t][i]);
    }
    __syncthreads();
    int rowBase = blockIdx.x * 64;
    int rowsHere = M - rowBase; if (rowsHere > 64) rowsHere = 64;
    int totalVec = rowsHere * (DOUT / 8);
    for (int idx = tid; idx < totalVec; idx += 256) {
        int r = idx / (DOUT / 8), c8 = idx % (DOUT / 8);
        uint4 v = *(const uint4*)&Ylds[r * LDW + c8 * 8];
        *(uint4*)(Y + (size_t)(rowBase + r) * DOUT + c8 * 8) = v;
    }
}

// ---------------- layer-1 MFMA GEMM reading raw x (dtype per flag) with PE fused ----------------
__global__ __launch_bounds__(256) void gemm_mfma_x_k(
    const void* __restrict__ X, const ushort_t* __restrict__ Wt,
    ushort_t* __restrict__ Y, int M, const void* __restrict__ pe,
    const int* __restrict__ flagp) {
    constexpr int K = 96, DOUT = 384, NT = DOUT / 16, LDW = DOUT + 8;
    __shared__ __align__(16) ushort_t Ylds[64 * LDW];
    __shared__ float pes[96];
    int isf = *flagp;
    int tid = threadIdx.x;
    if (tid < 96) pes[tid] = ldf(pe, tid, isf);
    __syncthreads();
    int wave = tid >> 6, lane = tid & 63;
    int q = lane >> 4, l15 = lane & 15;
    int arow = blockIdx.x * 64 + wave * 16 + l15;
    int rowc = arow < M ? arow : M - 1;
    f32x4 acc[NT];
#pragma unroll
    for (int t = 0; t < NT; ++t) acc[t] = (f32x4){0.f, 0.f, 0.f, 0.f};
#pragma unroll
    for (int kc = 0; kc < K; kc += 32) {
        float va[8];
        size_t base = (size_t)rowc * K + kc + q * 8;
        if (isf) {
            float4 u0 = *(const float4*)((const float*)X + base);
            float4 u1 = *(const float4*)((const float*)X + base + 4);
            va[0] = u0.x; va[1] = u0.y; va[2] = u0.z; va[3] = u0.w;
            va[4] = u1.x; va[5] = u1.y; va[6] = u1.z; va[7] = u1.w;
        } else {
            const ushort_t* xp = (const ushort_t*)X + base;
#pragma unroll
            for (int i = 0; i < 8; ++i) va[i] = bf2f(xp[i]);
        }
        bf16x8 a;
        short* ap = (short*)&a;
#pragma unroll
        for (int i = 0; i < 8; ++i) ap[i] = (short)f2bf(va[i] + pes[kc + q * 8 + i]);
#pragma unroll
        for (int t = 0; t < NT; ++t) {
            bf16x8 b = *(const bf16x8*)(Wt + (size_t)(t * 16 + l15) * K + kc + q * 8);
            acc[t] = __builtin_amdgcn_mfma_f32_16x16x32_bf16(a, b, acc[t], 0, 0, 0);
        }
    }
    int ldsRowBase = wave * 16 + q * 4;
#pragma unroll
    for (int t = 0; t < NT; ++t) {
        int col = t * 16 + l15;
#pragma unroll
        for (int i = 0; i < 4; ++i) Ylds[(ldsRowBase + i) * LDW + col] = f2bf(acc[t][i]);
    }
    __syncthreads();
    int rowBase = blockIdx.x * 64;
    int rowsHere = M - rowBase; if (rowsHere > 64) rowsHere = 64;
    int totalVec = rowsHere * (DOUT / 8);
    for (int idx = tid; idx < totalVec; idx += 256) {
        int r = idx / (DOUT / 8), c8 = idx % (DOUT / 8);
        uint4 v = *(const uint4*)&Ylds[r * LDW + c8 * 8];
        *(uint4*)(Y + (size_t)(rowBase + r) * DOUT + c8 * 8) = v;
    }
}

// ---------------- gather4: exact round-5 version (28 VGPR, best measured) ----------------
__device__ __forceinline__ void gather4(
    const uint2* __restrict__ pairs, const ushort_t* __restrict__ base, int ldY,
    int e0, int e1, float& out0, float& out1) {
    float a0 = 0.f, a1 = 0.f, b0 = 0.f, b1 = 0.f;
    float c0 = 0.f, c1 = 0.f, d0 = 0.f, d1 = 0.f;
    int e = e0;
    for (; e + 4 <= e1; e += 4) {
        uint2 p0 = pairs[e], p1 = pairs[e + 1], p2 = pairs[e + 2], p3 = pairs[e + 3];
        unsigned v0 = *(const unsigned*)(base + (size_t)p0.x * ldY);
        unsigned v1 = *(const unsigned*)(base + (size_t)p1.x * ldY);
        unsigned v2 = *(const unsigned*)(base + (size_t)p2.x * ldY);
        unsigned v3 = *(const unsigned*)(base + (size_t)p3.x * ldY);
        float w0 = __uint_as_float(p0.y), w1 = __uint_as_float(p1.y);
        float w2 = __uint_as_float(p2.y), w3 = __uint_as_float(p3.y);
        a0 += w0 * bf2f((ushort_t)(v0 & 0xffffu)); a1 += w0 * bf2f((ushort_t)(v0 >> 16));
        b0 += w1 * bf2f((ushort_t)(v1 & 0xffffu)); b1 += w1 * bf2f((ushort_t)(v1 >> 16));
        c0 += w2 * bf2f((ushort_t)(v2 & 0xffffu)); c1 += w2 * bf2f((ushort_t)(v2 >> 16));
        d0 += w3 * bf2f((ushort_t)(v3 & 0xffffu)); d1 += w3 * bf2f((ushort_t)(v3 >> 16));
    }
    for (; e < e1; ++e) {
        uint2 p = pairs[e];
        unsigned v = *(const unsigned*)(base + (size_t)p.x * ldY);
        float w = __uint_as_float(p.y);
        a0 += w * bf2f((ushort_t)(v & 0xffffu)); a1 += w * bf2f((ushort_t)(v >> 16));
    }
    out0 = (a0 + b0) + (c0 + d0);
    out1 = (a1 + b1) + (c1 + d1);
}

// ---------------- fused prop+combine: 512 threads, 4 in-waves + 4 out-waves, 4 nodes/block ----------------
__global__ __launch_bounds__(512) void prop_combine_k(
    const ushort_t* __restrict__ Y, int ldY,
    const int* __restrict__ offI, const uint2* __restrict__ prI,
    const int* __restrict__ offO, const uint2* __restrict__ prO,
    const void* __restrict__ Cin, const void* __restrict__ Cout,
    const float* __restrict__ bin, const float* __restrict__ bout,
    const ushort_t* __restrict__ res, int ldR, int colR, const float* __restrict__ res_b,
    ushort_t* __restrict__ H, int M, int relu, const int* __restrict__ flagp) {
    __shared__ float sOut[4][128];
    int isf = *flagp;
    int w = threadIdx.x >> 6;      // 0..7
    int lane = threadIdx.x & 63;
    int slot = w & 3;
    int node = blockIdx.x * 4 + slot;
    bool outSide = (w >= 4);
    float a0 = 0.f, a1 = 0.f;
    if (node < M) {
        if (outSide) gather4(prO, Y + 128 + lane * 2, ldY, offO[node], offO[node + 1], a0, a1);
        else         gather4(prI, Y + lane * 2,       ldY, offI[node], offI[node + 1], a0, a1);
    }
    if (outSide) { sOut[slot][lane * 2] = a0; sOut[slot][lane * 2 + 1] = a1; }
    __syncthreads();
    if (!outSide && node < M) {
        float o0 = sOut[slot][lane * 2], o1 = sOut[slot][lane * 2 + 1];
        int j = lane * 2;
        float ci = ldf(Cin, node, isf), co = ldf(Cout, node, isf);
        float r0 = bf2f(res[(size_t)node * ldR + colR + j]);
        float r1 = bf2f(res[(size_t)node * ldR + colR + j + 1]);
        float v0 = ci * (a0 + bin[j])     + co * (o0 + bout[j])     + r0;
        float v1 = ci * (a1 + bin[j + 1]) + co * (o1 + bout[j + 1]) + r1;
        if (res_b) { v0 += res_b[j]; v1 += res_b[j + 1]; }
        if (relu) { v0 = fmaxf(v0, 0.f); v1 = fmaxf(v1, 0.f); }
        *(unsigned*)(H + (size_t)node * 128 + j) =
            ((unsigned)f2bf(v1) << 16) | (unsigned)f2bf(v0);
    }
}

// ---------------- decoder: normalize + MFMA logits (classes=rows) + coalesced writes ----------------
__global__ __launch_bounds__(256) void decoder_mfma_k(
    const ushort_t* __restrict__ h3, const ushort_t* __restrict__ Wdt,  // [256][128] bf16
    const float* __restrict__ biasDec, void* __restrict__ d_out, int M,
    const int* __restrict__ flagp) {
    __shared__ ushort_t embLds[64 * 136];
    __shared__ float sb[256];
    int isf = *flagp;
    int tid = threadIdx.x;
    sb[tid] = biasDec[tid];
    int rowBase = blockIdx.x * 64;
    {
        int r = tid >> 2;
        int c0 = (tid & 3) * 32;
        int grow = rowBase + r;
        uint4 u[4] = {};
        if (grow < M) {
            const uint4* p = (const uint4*)(h3 + (size_t)grow * 128 + c0);
            u[0] = p[0]; u[1] = p[1]; u[2] = p[2]; u[3] = p[3];
        }
        float v[32];
#pragma unroll
        for (int b = 0; b < 4; ++b) {
            unsigned w[4] = {u[b].x, u[b].y, u[b].z, u[b].w};
#pragma unroll
            for (int i = 0; i < 4; ++i) {
                v[b * 8 + 2 * i]     = bf2f((ushort_t)(w[i] & 0xffffu));
                v[b * 8 + 2 * i + 1] = bf2f((ushort_t)(w[i] >> 16));
            }
        }
        float ss = 0.f;
#pragma unroll
        for (int i = 0; i < 32; ++i) ss += v[i] * v[i];
        ss += __shfl_xor(ss, 1, 64);
        ss += __shfl_xor(ss, 2, 64);
        float inv = 1.0f / fmaxf(sqrtf(ss), 1e-12f);
#pragma unroll
        for (int i = 0; i < 32; ++i) v[i] *= inv;
        unsigned* lp = (unsigned*)&embLds[r * 136 + c0];
#pragma unroll
        for (int i = 0; i < 16; ++i)
            lp[i] = ((unsigned)f2bf(v[2 * i + 1]) << 16) | (unsigned)f2bf(v[2 * i]);
    }
    __syncthreads();
    {
        int rowsHere = M - rowBase; if (rowsHere > 64) rowsHere = 64;
        int total = rowsHere * 128;
        if (isf) {
            float* dst = (float*)d_out + (size_t)M * 256 + (size_t)rowBase * 128;
            for (int idx = tid * 4; idx < total; idx += 1024) {
                int r = idx >> 7, c = idx & 127;
                const ushort_t* sp = &embLds[r * 136 + c];
                float4 o = make_float4(bf2f(sp[0]), bf2f(sp[1]), bf2f(sp[2]), bf2f(sp[3]));
                *(float4*)(dst + idx) = o;
            }
        } else {
            ushort_t* dst = (ushort_t*)d_out + (size_t)M * 256 + (size_t)rowBase * 128;
            for (int idx = tid * 4; idx < total; idx += 1024) {
                int r = idx >> 7, c = idx & 127;
                uint2 o = *(const uint2*)&embLds[r * 136 + c];
                *(uint2*)(dst + idx) = o;
            }
        }
    }
    int wave = tid >> 6, lane = tid & 63, q = lane >> 4, l15 = lane & 15;
    f32x4 acc[16];
#pragma unroll
    for (int t = 0; t < 16; ++t) acc[t] = (f32x4){0.f, 0.f, 0.f, 0.f};
    int ldsRow = wave * 16 + l15;
#pragma unroll
    for (int kc = 0; kc < 128; kc += 32) {
        bf16x8 a = *(const bf16x8*)(&embLds[ldsRow * 136 + kc + q * 8]);
#pragma unroll
        for (int t = 0; t < 16; ++t) {
            bf16x8 b = *(const bf16x8*)(Wdt + (size_t)(t * 16 + l15) * 128 + kc + q * 8);
            acc[t] = __builtin_amdgcn_mfma_f32_16x16x32_bf16(b, a, acc[t], 0, 0, 0);
        }
    }
    int node = rowBase + wave * 16 + l15;
#pragma unroll
    for (int t = 0; t < 16; ++t) {
#pragma unroll
        for (int i = 0; i < 4; ++i) acc[t][i] += sb[t * 16 + q * 4 + i];
    }
    float mx = acc[0][0];
#pragma unroll
    for (int t = 0; t < 16; ++t) {
#pragma unroll
        for (int i = 0; i < 4; ++i) mx = fmaxf(mx, acc[t][i]);
    }
    mx = fmaxf(mx, __shfl_xor(mx, 16, 64));
    mx = fmaxf(mx, __shfl_xor(mx, 32, 64));
    float sm = 0.f;
#pragma unroll
    for (int t = 0; t < 16; ++t) {
#pragma unroll
        for (int i = 0; i < 4; ++i) sm += __expf(acc[t][i] - mx);
    }
    sm += __shfl_xor(sm, 16, 64);
    sm += __shfl_xor(sm, 32, 64);
    float offv = mx + __logf(sm);
    if (node < M) {
        if (isf) {
            float* op = (float*)d_out + (size_t)node * 256 + q * 4;
#pragma unroll
            for (int t = 0; t < 16; ++t) {
                float4 o = make_float4(acc[t][0] - offv, acc[t][1] - offv,
                                       acc[t][2] - offv, acc[t][3] - offv);
                *(float4*)(op + t * 16) = o;
            }
        } else {
            ushort_t* op = (ushort_t*)d_out + (size_t)node * 256 + q * 4;
#pragma unroll
            for (int t = 0; t < 16; ++t) {
                unsigned lo = ((unsigned)f2bf(acc[t][1] - offv) << 16) | (unsigned)f2bf(acc[t][0] - offv);
                unsigned hi = ((unsigned)f2bf(acc[t][3] - offv) << 16) | (unsigned)f2bf(acc[t][2] - offv);
                *(uint2*)(op + t * 16) = make_uint2(lo, hi);
            }
        }
    }
}

extern "C" void kernel_launch(void* const* d_in, const int* in_sizes, int n_in,
                              void* d_out, int out_size, void* d_ws, size_t ws_size,
                              hipStream_t stream) {
    const int N = in_sizes[0] / 96;
    const int E = in_sizes[2];

    const void* x      = d_in[0];
    const int*  ei_in  = (const int*)d_in[1];
    const void* ew_in  = d_in[2];
    const int*  ei_out = (const int*)d_in[3];
    const void* ew_out = d_in[4];
    const void* pe     = d_in[5];

    const void *W_mi[3], *W_mo[3], *W_sk[3], *b_mi[3], *b_mo[3], *b_si[3], *b_so[3], *C_i[3], *C_o[3];
    for (int l = 0; l < 3; ++l) {
        int base = 6 + l * 9;
        W_mi[l] = d_in[base + 0];
        W_mo[l] = d_in[base + 1];
        W_sk[l] = d_in[base + 2];
        b_mi[l] = d_in[base + 3];
        b_mo[l] = d_in[base + 4];
        b_si[l] = d_in[base + 5];
        b_so[l] = d_in[base + 6];
        C_i[l]  = d_in[base + 7];
        C_o[l]  = d_in[base + 8];
    }
    const void* res1_W = d_in[33];
    const void* res1_b = d_in[34];
    const void* dec_W  = d_in[35];
    const void* dec_b  = d_in[36];

    // ---- workspace (~80 MB) ----
    char* ws = (char*)d_ws;
    size_t off = 0;
    auto alloc = [&](size_t bytes) -> void* {
        void* p = ws + off;
        off = (off + bytes + 255) & ~(size_t)255;
        return p;
    };
    const int nChunks = (N + 1023) / 1024;
    int*   flag    = (int*)alloc(4);
    int*   off_in  = (int*)alloc((size_t)(N + 1) * 4);
    int*   off_out = (int*)alloc((size_t)(N + 1) * 4);
    int*   cntBlk  = (int*)alloc((size_t)4 * N * 4);  // cnt_in|cur_in|cnt_out|cur_out contiguous
    int*   cnt_in  = cntBlk, *cur_in = cntBlk + N, *cnt_out = cntBlk + 2 * N, *cur_out = cntBlk + 3 * N;
    uint2* pr_in   = (uint2*)alloc((size_t)E * 8);
    uint2* pr_out  = (uint2*)alloc((size_t)E * 8);
    int*   sums    = (int*)alloc((size_t)2 * nChunks * 4);
    ushort_t* Wt1  = (ushort_t*)alloc((size_t)384 * 96 * 2);
    ushort_t* Wt2  = (ushort_t*)alloc((size_t)256 * 128 * 2);
    ushort_t* Wt3  = (ushort_t*)alloc((size_t)256 * 128 * 2);
    ushort_t* Wdt  = (ushort_t*)alloc((size_t)256 * 128 * 2);
    float* biasBlk = (float*)alloc((size_t)1152 * 4);
    float* bin1 = biasBlk, *bout1 = biasBlk + 128, *bin2 = biasBlk + 256, *bout2 = biasBlk + 384;
    float* bin3 = biasBlk + 512, *bout3 = biasBlk + 640, *res1b = biasBlk + 768, *decb = biasBlk + 896;
    ushort_t* Yb  = (ushort_t*)alloc((size_t)N * 384 * 2);
    ushort_t* H1  = (ushort_t*)alloc((size_t)N * 128 * 2);
    ushort_t* H2  = (ushort_t*)alloc((size_t)N * 128 * 2);
    ushort_t* H3  = H1;  // H1 dead once layer-2 combine produced H2

    // ---- dtype probe ----
    probe_dtype_k<<<1, 256, 0, stream>>>(x, flag);

    // ---- CSR build ----
    hipMemsetAsync(cntBlk, 0, (size_t)4 * N * 4, stream);
    int egrid = (E + 255) / 256;
    count_dst_k<<<dim3(egrid, 2), 256, 0, stream>>>(ei_in, ei_out, cnt_in, cnt_out, E);
    {
        dim3 g(nChunks, 2);
        scan1_k<<<g, 256, 0, stream>>>(cnt_in, cnt_out, off_in, off_out, sums, N, nChunks);
        scan2_k<<<1, 256, 0, stream>>>(sums, nChunks);
        scan3_k<<<g, 256, 0, stream>>>(off_in, off_out, sums, N, nChunks, E);
    }
    fill_csr_k<<<dim3(egrid, 2), 256, 0, stream>>>(ei_in, ew_in, ei_out, ew_out,
                                                   off_in, off_out, cur_in, cur_out,
                                                   pr_in, pr_out, E, flag);

    // ---- fused weight prep (7 band jobs + decoder transpose in one launch) ----
    {
        PrepJobs pj;
        int blk = 0;
        auto addBand = [&](const void* A, const void* B, ushort_t* dst, int K, int colOff, int n, int idx) {
            pj.j[idx] = {A, B, dst, K, colOff, n, blk, 0};
            blk += (n + 255) / 256;
        };
        addBand(W_mi[0], W_sk[0], Wt1, 96, 0,   128 * 96, 0);
        addBand(W_mo[0], W_sk[0], Wt1, 96, 128, 128 * 96, 1);
        addBand(res1_W, nullptr,  Wt1, 96, 256, 128 * 96, 2);
        addBand(W_mi[1], W_sk[1], Wt2, 128, 0,   128 * 128, 3);
        addBand(W_mo[1], W_sk[1], Wt2, 128, 128, 128 * 128, 4);
        addBand(W_mi[2], W_sk[2], Wt3, 128, 0,   128 * 128, 5);
        addBand(W_mo[2], W_sk[2], Wt3, 128, 128, 128 * 128, 6);
        pj.j[7] = {dec_W, nullptr, Wdt, 128, 0, 128 * 256, blk, 1};
        blk += (128 * 256 + 255) / 256;
        prep_all_k<<<blk, 256, 0, stream>>>(pj, flag);
    }
    {
        BiasJobs jb;
        jb.j[0] = {b_mi[0], b_si[0], bin1, 128};
        jb.j[1] = {b_mo[0], b_so[0], bout1, 128};
        jb.j[2] = {b_mi[1], b_si[1], bin2, 128};
        jb.j[3] = {b_mo[1], b_so[1], bout2, 128};
        jb.j[4] = {b_mi[2], b_si[2], bin3, 128};
        jb.j[5] = {b_mo[2], b_so[2], bout3, 128};
        jb.j[6] = {res1_b, nullptr, res1b, 128};
        jb.j[7] = {dec_b, nullptr, decb, 256};
        prep_bias_k<<<8, 256, 0, stream>>>(jb, flag);
    }

    int gBlocks = (N + 63) / 64;
    int pgrid = (N + 3) / 4;

    // ---- layer 1: fused x+PE 96x384 GEMM (main_in | main_out | res) ----
    gemm_mfma_x_k<<<gBlocks, 256, 0, stream>>>(x, Wt1, Yb, N, pe, flag);
    prop_combine_k<<<pgrid, 512, 0, stream>>>(Yb, 384,
        off_in, pr_in, off_out, pr_out,
        C_i[0], C_o[0], bin1, bout1, Yb, 384, 256, res1b, H1, N, 1, flag);
    // ---- layer 2 ----
    gemm_mfma_k<128, 256><<<gBlocks, 256, 0, stream>>>(H1, Wt2, Yb, N);
    prop_combine_k<<<pgrid, 512, 0, stream>>>(Yb, 256,
        off_in, pr_in, off_out, pr_out,
        C_i[1], C_o[1], bin2, bout2, H1, 128, 0, (const float*)nullptr, H2, N, 1, flag);
    // ---- layer 3 ----
    gemm_mfma_k<128, 256><<<gBlocks, 256, 0, stream>>>(H2, Wt3, Yb, N);
    prop_combine_k<<<pgrid, 512, 0, stream>>>(Yb, 256,
        off_in, pr_in, off_out, pr_out,
        C_i[2], C_o[2], bin3, bout3, H2, 128, 0, (const float*)nullptr, H3, N, 0, flag);
    // ---- decoder ----
    decoder_mfma_k<<<gBlocks, 256, 0, stream>>>(H3, Wdt, decb, d_out, N, flag);
}